// Round 5
// baseline (151.574 us; speedup 1.0000x reference)
//
#include <hip/hip_runtime.h>
#include <cstdint>

#define SEQ_LEN 2048
#define DIM 1024
#define NHEAD 16
#define DHEAD 64
#define QKV_LD (3 * DIM)

typedef unsigned short u16;
typedef short bf16x8 __attribute__((ext_vector_type(8)));
typedef float f32x4 __attribute__((ext_vector_type(4)));

__device__ __forceinline__ u16 f2bf(float f) {
    union { float f; unsigned u; } v;
    v.f = f;
    unsigned r = v.u + 0x7fff + ((v.u >> 16) & 1);  // RNE
    return (u16)(r >> 16);
}

// async global -> LDS, 16 B per lane (global_load_lds_dwordx4)
__device__ __forceinline__ void load_lds16(const void* g, void* l) {
    __builtin_amdgcn_global_load_lds(
        (const __attribute__((address_space(1))) void*)g,
        (__attribute__((address_space(3))) void*)l, 16, 0, 0);
}

// ---------------------------------------------------------------------------
// Fused prep: [0,2048) cast x -> bf16 ; [2048,5120) transpose Wqkv ;
// [5120,6144) transpose Wout. Branch is block-uniform.
// ---------------------------------------------------------------------------
__device__ __forceinline__ void transpose_tile(const float* __restrict__ W,
                                               u16* __restrict__ Wt, int K, int N,
                                               int bx, int by, int t, float (*tile)[33]) {
    const int n0 = bx * 32, k0 = by * 32;
    const int tx = t & 31, ty = t >> 5;  // 32 x 8
#pragma unroll
    for (int i = 0; i < 32; i += 8)
        tile[ty + i][tx] = W[(size_t)(k0 + ty + i) * N + n0 + tx];
    __syncthreads();
#pragma unroll
    for (int i = 0; i < 32; i += 8)
        Wt[(size_t)(n0 + ty + i) * K + k0 + tx] = f2bf(tile[tx][ty + i]);
}

__global__ __launch_bounds__(256) void prep_k(const float* __restrict__ x,
                                              const float* __restrict__ Wqkv,
                                              const float* __restrict__ Wout,
                                              u16* __restrict__ xb,
                                              u16* __restrict__ Wqkvt,
                                              u16* __restrict__ Woutt) {
    __shared__ float tile[32][33];
    const int b = blockIdx.x;
    const int t = threadIdx.x;
    if (b < 2048) {  // cast x: 2048*256 threads x 1 float4 = 2048x1024 exactly
        const int i = b * 256 + t;
        const float4 v = reinterpret_cast<const float4*>(x)[i];
        const unsigned p0 = (unsigned)f2bf(v.x) | ((unsigned)f2bf(v.y) << 16);
        const unsigned p1 = (unsigned)f2bf(v.z) | ((unsigned)f2bf(v.w) << 16);
        reinterpret_cast<uint2*>(xb)[i] = make_uint2(p0, p1);
    } else if (b < 5120) {  // Wqkv [1024,3072] -> [3072,1024]
        const int b2 = b - 2048;
        transpose_tile(Wqkv, Wqkvt, DIM, QKV_LD, b2 % 96, b2 / 96, t, tile);
    } else {  // Wout [1024,1024] -> [1024,1024]^T
        const int b3 = b - 5120;
        transpose_tile(Wout, Woutt, DIM, DIM, b3 & 31, b3 >> 5, t, tile);
    }
}

// ---------------------------------------------------------------------------
// bf16 MFMA GEMM: C[M,N] = A[M,K] @ Bt[N,K]^T. Tile BM x BN x BK.
// Double-buffered LDS via global_load_lds, one barrier per K-iter, prefetch
// DMA issued right after the barrier. 4 waves: 2(m) x 2(n).
// MODE 0: bf16 output. MODE 1: fp32 output + bias.
// ---------------------------------------------------------------------------
template <int MODE, int BM, int BN, int BK>
__global__ __launch_bounds__(256) void gemm_bf16(const u16* __restrict__ A,
                                                 const u16* __restrict__ Bt,
                                                 const float* __restrict__ bias,
                                                 void* __restrict__ Cout,
                                                 int M, int N, int K) {
    constexpr int AI = BM / 32;   // m-frags per wave
    constexpr int BJ = BN / 32;   // n-frags per wave
    constexpr int ASZ = BM * BK;  // u16 per A buffer
    constexpr int BSZ = BN * BK;
    __shared__ u16 As[2 * ASZ];
    __shared__ u16 Bs[2 * BSZ];

    const int t = threadIdx.x;
    const int lane = t & 63;
    const int quad = lane >> 4;
    const int l15 = lane & 15;
    const int w = t >> 6;
    const int wm = (w & 1) * (BM / 2);
    const int wn = (w >> 1) * (BN / 2);
    const int m0 = blockIdx.y * BM;
    const int n0 = blockIdx.x * BN;
    const int sr = t >> 2;        // staging row 0..63
    const int sc = (t & 3) << 3;  // staging k offset

    const u16* Ab = A + (size_t)(m0 + sr) * K + sc;
    const u16* Bb = Bt + (size_t)(n0 + sr) * K + sc;

    auto stage = [&](int buf, int k0) {
#pragma unroll
        for (int kc = 0; kc < BK / 32; ++kc) {
#pragma unroll
            for (int c = 0; c < BM / 64; ++c)
                load_lds16(Ab + (size_t)(c * 64) * K + k0 + kc * 32,
                           &As[buf * ASZ + kc * BM * 32 + c * 2048 + t * 8]);
#pragma unroll
            for (int c = 0; c < BN / 64; ++c)
                load_lds16(Bb + (size_t)(c * 64) * K + k0 + kc * 32,
                           &Bs[buf * BSZ + kc * BN * 32 + c * 2048 + t * 8]);
        }
    };

    stage(0, 0);
    f32x4 acc[AI][BJ] = {};

    const int niter = K / BK;
    for (int it = 0; it < niter; ++it) {
        const int cur = it & 1, nxt = cur ^ 1;
        __syncthreads();  // buf[cur] DMA drained; buf[nxt] readers done
        if (it + 1 < niter) stage(nxt, (it + 1) * BK);
#pragma unroll
        for (int kc = 0; kc < BK / 32; ++kc) {
            bf16x8 af[AI], bfr[BJ];
#pragma unroll
            for (int i = 0; i < AI; ++i)
                af[i] = *reinterpret_cast<const bf16x8*>(
                    &As[cur * ASZ + kc * BM * 32 + (wm + i * 16 + l15) * 32 + quad * 8]);
#pragma unroll
            for (int j = 0; j < BJ; ++j)
                bfr[j] = *reinterpret_cast<const bf16x8*>(
                    &Bs[cur * BSZ + kc * BN * 32 + (wn + j * 16 + l15) * 32 + quad * 8]);
#pragma unroll
            for (int i = 0; i < AI; ++i)
#pragma unroll
                for (int j = 0; j < BJ; ++j)
                    acc[i][j] =
                        __builtin_amdgcn_mfma_f32_16x16x32_bf16(af[i], bfr[j], acc[i][j], 0, 0, 0);
        }
    }

#pragma unroll
    for (int j = 0; j < BJ; ++j) {
        const int col = n0 + wn + j * 16 + l15;
        float bv = 0.f;
        if constexpr (MODE == 1) bv = bias[col];
#pragma unroll
        for (int i = 0; i < AI; ++i) {
            const int row = m0 + wm + i * 16 + quad * 4;
#pragma unroll
            for (int r = 0; r < 4; ++r) {
                const float v = acc[i][j][r];
                if constexpr (MODE == 1)
                    ((float*)Cout)[(size_t)(row + r) * N + col] = v + bv;
                else
                    ((u16*)Cout)[(size_t)(row + r) * N + col] = f2bf(v);
            }
        }
    }
}

// ---------------------------------------------------------------------------
// MFMA causal flash attention, no-max softmax, NO in-loop DMA.
// BM=32 q-rows x 1 head per block; 1024 blocks heavy-first (LPT).
// 4 waves = 2(q-half of 16) x 2(kv-half of 32). Single-buffered Ks/Vt:
// per tile, K+V for tile jt+1 are prefetched into REGISTERS right away,
// and written to LDS between two drain-free barriers after the PV MFMAs.
// LDS = 21.5 KB -> ~6 blocks/CU (VGPR-capped), ~24 waves/CU.
// ---------------------------------------------------------------------------
__global__ __launch_bounds__(256) void attn_mfma(const u16* __restrict__ qkv,
                                                 u16* __restrict__ O) {
    constexpr int PSTR = 40;
    __shared__ u16 SM[2560 + 4096 + 4096];  // Ps | Ks | Vt = 21504 B
    u16* Ps = SM;                 // [4 w][16 q][PSTR]; prologue: Q staging [2ch][32q][32d]
    u16* Ks = SM + 2560;          // [2 ch][64 kv][32 d]
    u16* Vt = SM + 2560 + 4096;   // [64 d][64 kv], 8-group XOR swizzle by d&7
    float* Ored = (float*)SM;     // epilogue overlay [32 q][66]
    float* Lred = Ored + 32 * 66; // [2 wk][32 q]

    const int b = blockIdx.x;
    const int i = 63 - (b >> 4);  // q-subtile, heavy first
    const int h = b & 15;
    const int q0 = i * 32;
    const int jmax = i >> 1;

    const int t = threadIdx.x;
    const int lane = t & 63;
    const int quad = lane >> 4;
    const int l15 = lane & 15;
    const int w = t >> 6;
    const int wq = w >> 1;  // q half
    const int wk = w & 1;   // kv half

    const int sr = t >> 2;        // K staging: row 0..63
    const int sc = (t & 3) << 3;  // K staging: d offset
    const int vp = (t & 31) * 2;  // V staging: kv pair base
    const int vq = (t >> 5) * 8;  // V staging: d base

    // ---- stage Q via DMA into Ps region; K0/V0 -> regs ----
    load_lds16(qkv + (size_t)(q0 + ((t >> 2) & 31)) * QKV_LD + h * DHEAD + (t >> 7) * 32 + sc,
               &SM[t * 8]);
    const u16* kp0 = qkv + (size_t)sr * QKV_LD + DIM + h * DHEAD + sc;
    uint4 ka = *reinterpret_cast<const uint4*>(kp0);
    uint4 kb = *reinterpret_cast<const uint4*>(kp0 + 32);
    const u16* vp0 = qkv + (size_t)vp * QKV_LD + 2 * DIM + h * DHEAD + vq;
    uint4 va = *reinterpret_cast<const uint4*>(vp0);
    uint4 vb = *reinterpret_cast<const uint4*>(vp0 + QKV_LD);

    __syncthreads();  // Q DMA drained
    const bf16x8 qf0 = *reinterpret_cast<const bf16x8*>(&SM[(wq * 16 + l15) * 32 + quad * 8]);
    const bf16x8 qf1 =
        *reinterpret_cast<const bf16x8*>(&SM[1024 + (wq * 16 + l15) * 32 + quad * 8]);
    __syncthreads();  // all Q reads done before Ks/Vt/Ps writes

    // write K0/V0 to LDS (V transposed+swizzled, kv-paired b32 writes)
    auto writeKV = [&](const uint4& kA, const uint4& kB, const uint4& vA, const uint4& vB) {
        *reinterpret_cast<uint4*>(&Ks[t * 8]) = kA;
        *reinterpret_cast<uint4*>(&Ks[2048 + t * 8]) = kB;
        const unsigned a4[4] = {vA.x, vA.y, vA.z, vA.w};
        const unsigned b4[4] = {vB.x, vB.y, vB.z, vB.w};
#pragma unroll
        for (int idx = 0; idx < 8; ++idx) {
            const unsigned lo = (idx & 1) ? (a4[idx >> 1] >> 16) : (a4[idx >> 1] & 0xffffu);
            const unsigned hi = (idx & 1) ? (b4[idx >> 1] >> 16) : (b4[idx >> 1] & 0xffffu);
            const int d = vq + idx;
            const int pos = d * 64 + (((vp >> 3) ^ (d & 7)) << 3) + (vp & 7);
            *reinterpret_cast<unsigned*>(&Vt[pos]) = lo | (hi << 16);
        }
    };
    writeKV(ka, kb, va, vb);
    __syncthreads();  // Ks/Vt tile 0 visible

    f32x4 oacc[4] = {};
    float lsum[4] = {0.f, 0.f, 0.f, 0.f};
    u16* Pw = Ps + w * 16 * PSTR;
    const int rowl_base = (i & 1) * 32 + wq * 16 + quad * 4;  // diag-tile local row
    constexpr float SCL = 0.18033688f;                        // (1/8)*log2(e)

    for (int jt = 0; jt <= jmax; ++jt) {
        if (jt < jmax) {  // prefetch next tile into regs (consumed after barrier below)
            const int j1 = (jt + 1) * 64;
            const u16* kp = qkv + (size_t)(j1 + sr) * QKV_LD + DIM + h * DHEAD + sc;
            ka = *reinterpret_cast<const uint4*>(kp);
            kb = *reinterpret_cast<const uint4*>(kp + 32);
            const u16* vpt = qkv + (size_t)(j1 + vp) * QKV_LD + 2 * DIM + h * DHEAD + vq;
            va = *reinterpret_cast<const uint4*>(vpt);
            vb = *reinterpret_cast<const uint4*>(vpt + QKV_LD);
        }

        // ---- S = Q @ K^T (wave: 16 qrows x 32 kvcols) ----
        f32x4 sacc[2] = {};
#pragma unroll
        for (int nn = 0; nn < 2; ++nn) {
            const int krow = (wk * 32 + nn * 16 + l15) * 32 + quad * 8;
            const bf16x8 kf0 = *reinterpret_cast<const bf16x8*>(&Ks[krow]);
            sacc[nn] = __builtin_amdgcn_mfma_f32_16x16x32_bf16(qf0, kf0, sacc[nn], 0, 0, 0);
            const bf16x8 kf1 = *reinterpret_cast<const bf16x8*>(&Ks[2048 + krow]);
            sacc[nn] = __builtin_amdgcn_mfma_f32_16x16x32_bf16(qf1, kf1, sacc[nn], 0, 0, 0);
        }

        // ---- no-max softmax; P stored truncated (cheap f32->bf16) ----
        const bool diag = (jt == jmax);
#pragma unroll
        for (int r = 0; r < 4; ++r) {
            float p0 = sacc[0][r] * SCL, p1 = sacc[1][r] * SCL;
            if (diag) {
                const int rowl = rowl_base + r;
                if (wk * 32 + l15 > rowl) p0 = -1e30f;
                if (wk * 32 + 16 + l15 > rowl) p1 = -1e30f;
            }
            p0 = exp2f(p0);
            p1 = exp2f(p1);
            lsum[r] += p0 + p1;
            Pw[(quad * 4 + r) * PSTR + l15] = (u16)(__float_as_uint(p0) >> 16);
            Pw[(quad * 4 + r) * PSTR + 16 + l15] = (u16)(__float_as_uint(p1) >> 16);
        }

        // ---- O += P @ V (per-wave Ps; wave's 32-kv slice) ----
        const bf16x8 pf = *reinterpret_cast<const bf16x8*>(&Pw[l15 * PSTR + quad * 8]);
#pragma unroll
        for (int nd = 0; nd < 4; ++nd) {
            const int dloc = nd * 16 + l15;
            const bf16x8 vf = *reinterpret_cast<const bf16x8*>(
                &Vt[dloc * 64 + (((wk * 4 + quad) ^ (dloc & 7)) << 3)]);
            oacc[nd] = __builtin_amdgcn_mfma_f32_16x16x32_bf16(pf, vf, oacc[nd], 0, 0, 0);
        }

        if (jt < jmax) {
            __syncthreads();  // all Ks/Vt reads of tile jt done (no DMA -> no drain)
            writeKV(ka, kb, va, vb);
            __syncthreads();  // tile jt+1 visible
        }
    }

    // ---- epilogue: reduce l over 16 lanes, combine kv-halves, normalize ----
#pragma unroll
    for (int r = 0; r < 4; ++r) {
        float l = lsum[r];
#pragma unroll
        for (int off = 1; off < 16; off <<= 1) l += __shfl_xor(l, off, 64);
        lsum[r] = l;
    }
    __syncthreads();  // main-loop LDS dead; overlays safe
    if (l15 == 0)
#pragma unroll
        for (int r = 0; r < 4; ++r) Lred[wk * 32 + wq * 16 + quad * 4 + r] = lsum[r];
    if (wk == 1)
#pragma unroll
        for (int nd = 0; nd < 4; ++nd)
#pragma unroll
            for (int r = 0; r < 4; ++r)
                Ored[(wq * 16 + quad * 4 + r) * 66 + nd * 16 + l15] = oacc[nd][r];
    __syncthreads();
    if (wk == 0) {
        float inv[4];
#pragma unroll
        for (int r = 0; r < 4; ++r) {
            const int rr = wq * 16 + quad * 4 + r;
            inv[r] = 1.0f / (Lred[rr] + Lred[32 + rr]);
        }
#pragma unroll
        for (int nd = 0; nd < 4; ++nd)
#pragma unroll
            for (int r = 0; r < 4; ++r) {
                const int rr = wq * 16 + quad * 4 + r;
                O[(size_t)(q0 + rr) * DIM + h * DHEAD + nd * 16 + l15] =
                    f2bf((oacc[nd][r] + Ored[rr * 66 + nd * 16 + l15]) * inv[r]);
            }
    }
}

// ---------------------------------------------------------------------------
extern "C" void kernel_launch(void* const* d_in, const int* in_sizes, int n_in,
                              void* d_out, int out_size, void* d_ws, size_t ws_size,
                              hipStream_t stream) {
    const float* x = (const float*)d_in[0];     // [2048,1024]
    const float* Wqkv = (const float*)d_in[1];  // [1024,3072]
    const float* Wout = (const float*)d_in[2];  // [1024,1024]
    const float* bias = (const float*)d_in[3];  // [1024]
    float* out = (float*)d_out;

    char* ws = (char*)d_ws;
    u16* xb = (u16*)ws;                     // 4 MB
    u16* Wqkvt = (u16*)(ws + (4u << 20));   // 6 MB  [3072,1024]
    u16* Woutt = (u16*)(ws + (10u << 20));  // 2 MB  [1024,1024]
    u16* qkvb = (u16*)(ws + (12u << 20));   // 12 MB [2048,3072]
    u16* Ob = (u16*)(ws + (24u << 20));     // 4 MB  [2048,1024]

    // fused prep: cast x (2048 blk) + transpose Wqkv (3072) + Wout (1024)
    prep_k<<<dim3(6144), 256, 0, stream>>>(x, Wqkv, Wout, xb, Wqkvt, Woutt);

    // qkv = x @ Wqkv (bf16 out): 128x64 tiles, BK=32 (24 KB LDS -> 5 blk/CU)
    gemm_bf16<0, 128, 64, 32><<<dim3(QKV_LD / 64, SEQ_LEN / 128), 256, 0, stream>>>(
        xb, Wqkvt, nullptr, qkvb, SEQ_LEN, QKV_LD, DIM);

    // causal attention: 64 q-subtiles x 16 heads = 1024 blocks, heavy-first
    attn_mfma<<<dim3(64 * NHEAD), 256, 0, stream>>>(qkvb, Ob);

    // out = O @ Wout + bias (fp32 out): 64x64 tiles, BK=64 (32 KB LDS)
    gemm_bf16<1, 64, 64, 64><<<dim3(DIM / 64, SEQ_LEN / 64), 256, 0, stream>>>(
        Ob, Woutt, bias, out, SEQ_LEN, DIM, DIM);
}